// Round 4
// baseline (212.128 us; speedup 1.0000x reference)
//
#include <hip/hip_runtime.h>
#include <math.h>

typedef float f4 __attribute__((ext_vector_type(4)));

#define Bc 4
#define Vc 4
#define Hc 256
#define Wc 384
#define HWc (Hc*Wc)               // 98304
#define TOTc (Bc*Vc*HWc)          // 1572864
#define SCALE_MIN_c 1e-05f
#define SCALE_MAX_c 30.0f
#define EPS_c 1e-08f

// Output section offsets (in floats)
#define MEANS_OFF  ((size_t)0)
#define SCALES_OFF ((size_t)TOTc*3)
#define ROT_OFF    ((size_t)TOTc*6)
#define HARM_OFF   ((size_t)TOTc*10)
#define OPAC_OFF   ((size_t)TOTc*13)

// 4 pixels per thread; 256 threads/block -> 1024 pixels/block.
// HWc/1024 = 96 blocks per view; 16 views -> 1536 blocks. View is block-uniform.
#define BLOCKS_PER_VIEW (HWc/1024)   // 96

__global__ __launch_bounds__(256) void ga_kernel(
    const float* __restrict__ ext,    // (B,V,4,4)
    const float* __restrict__ intr,   // (B,V,3,3)
    const float* __restrict__ depths, // (B,V,H,W)
    const float* __restrict__ opac,   // (B,V,H,W)
    const float* __restrict__ raw,    // (B,V,H,W,12)
    float* __restrict__ out)
{
    const int tid  = threadIdx.x;
    const int bid  = blockIdx.x;
    const int view = bid / BLOCKS_PER_VIEW;                  // block-uniform
    const int pix0 = (bid - view * BLOCKS_PER_VIEW) * 1024 + tid * 4;
    const size_t g0 = (size_t)view * HWc + (size_t)pix0;

    // ---- issue ALL per-thread input loads first (max MLP, 14 in flight) ----
    const f4* rp = reinterpret_cast<const f4*>(raw + g0 * 12);
    f4 rw[12];
    #pragma unroll
    for (int i = 0; i < 12; i++) rw[i] = rp[i];
    const f4 dep4 = *reinterpret_cast<const f4*>(depths + g0);
    const f4 op4  = *reinterpret_cast<const f4*>(opac + g0);

    // ---- per-view constants, computed redundantly by every lane (uniform) ----
    const float* E = ext + view * 16;
    // Rc2w = Rw2c^T
    const float R0 = E[0], R1 = E[4], R2 = E[8];
    const float R3 = E[1], R4 = E[5], R5 = E[9];
    const float R6 = E[2], R7 = E[6], R8 = E[10];
    const float t0 = E[3], t1 = E[7], t2 = E[11];
    const float O0 = -(R0*t0 + R1*t1 + R2*t2);
    const float O1 = -(R3*t0 + R4*t1 + R5*t2);
    const float O2 = -(R6*t0 + R7*t1 + R8*t2);

    const float* I = intr + view * 9;
    const float a00 = I[0]*(1.0f/Wc), a01 = I[1]*(1.0f/Wc), a02 = I[2]*(1.0f/Wc);
    const float a10 = I[3]*(1.0f/Hc), a11 = I[4]*(1.0f/Hc), a12 = I[5]*(1.0f/Hc);
    const float a20 = I[6],           a21 = I[7],           a22 = I[8];
    const float det = a00*(a11*a22 - a12*a21)
                    - a01*(a10*a22 - a12*a20)
                    + a02*(a10*a21 - a11*a20);
    const float id = 1.0f / det;
    const float K0 = (a11*a22 - a12*a21)*id;
    const float K1 = (a02*a21 - a01*a22)*id;
    const float K2 = (a01*a12 - a02*a11)*id;
    const float K3 = (a12*a20 - a10*a22)*id;
    const float K4 = (a00*a22 - a02*a20)*id;
    const float K5 = (a02*a10 - a00*a12)*id;
    const float K6 = (a10*a21 - a11*a20)*id;
    const float K7 = (a01*a20 - a00*a21)*id;
    const float K8 = (a00*a11 - a01*a10)*id;

    const float det2 = a00*a11 - a01*a10;
    const float psx = 1.0f/Wc, psy = 1.0f/Hc;
    const float mult = 0.1f * ((a11*psx - a01*psy) + (-a10*psx + a00*psy)) / det2;

    // c2w quaternion from Rc2w (matches _mat_to_quat_wxyz); branches are wave-uniform
    const float m00 = R0, m01 = R1, m02 = R2;
    const float m10 = R3, m11 = R4, m12 = R5;
    const float m20 = R6, m21 = R7, m22 = R8;
    const float qa0 = sqrtf(fmaxf(0.0f, 1.0f + m00 + m11 + m22));
    const float qa1 = sqrtf(fmaxf(0.0f, 1.0f + m00 - m11 - m22));
    const float qa2 = sqrtf(fmaxf(0.0f, 1.0f - m00 + m11 - m22));
    const float qa3 = sqrtf(fmaxf(0.0f, 1.0f - m00 - m11 + m22));
    int idx = 0; float best = qa0, qsel = qa0;
    if (qa1 > best) { idx = 1; best = qa1; }
    if (qa2 > best) { idx = 2; best = qa2; }
    if (qa3 > best) { idx = 3; best = qa3; }
    float c0, c1, c2, c3;
    if (idx == 0)      { c0 = qa0*qa0;   c1 = m21 - m12; c2 = m02 - m20; c3 = m10 - m01; qsel = qa0; }
    else if (idx == 1) { c0 = m21 - m12; c1 = qa1*qa1;   c2 = m10 + m01; c3 = m02 + m20; qsel = qa1; }
    else if (idx == 2) { c0 = m02 - m20; c1 = m10 + m01; c2 = qa2*qa2;   c3 = m12 + m21; qsel = qa2; }
    else               { c0 = m10 - m01; c1 = m20 + m02; c2 = m21 + m12; c3 = qa3*qa3;   qsel = qa3; }
    const float dd = 1.0f / (2.0f * fmaxf(qsel, 0.1f));
    float q0 = c0*dd, q1 = c1*dd, q2 = c2*dd, q3 = c3*dd;
    const float qn = 1.0f / sqrtf(q0*q0 + q1*q1 + q2*q2 + q3*q3);
    const float aw = q0*qn, ax = q1*qn, ay = q2*qn, az = q3*qn;

    // ---- per-pixel work (4 pixels, same image row) ----
    const int h  = pix0 / Wc;
    const int w0 = pix0 - h * Wc;
    const float ybase = (h + 0.5f) * (1.0f/Hc);
    const float dv[4] = { dep4.x, dep4.y, dep4.z, dep4.w };

    f4 M[3], S[3], Hm[3], Rt[4];

    #pragma unroll
    for (int p = 0; p < 4; p++) {
        const f4 ra = rw[3*p + 0];   // raw[0..3]
        const f4 rb = rw[3*p + 1];   // raw[4..7]
        const f4 rc = rw[3*p + 2];   // raw[8..11]
        const float dep = dv[p];

        const float x = (w0 + p + 0.5f) * (1.0f/Wc) + ra.x * (1.0f/Wc);
        const float y = ybase + ra.y * (1.0f/Hc);

        // d_cam = normalize(Kinv @ (x,y,1))
        float dc0 = K0*x + K1*y + K2;
        float dc1 = K3*x + K4*y + K5;
        float dc2 = K6*x + K7*y + K8;
        const float inl = rsqrtf(dc0*dc0 + dc1*dc1 + dc2*dc2);
        dc0 *= inl; dc1 *= inl; dc2 *= inl;

        // d_world = Rc2w @ d_cam
        const float dw0 = R0*dc0 + R1*dc1 + R2*dc2;
        const float dw1 = R3*dc0 + R4*dc1 + R5*dc2;
        const float dw2 = R6*dc0 + R7*dc1 + R8*dc2;

        // means
        M[(3*p+0)>>2][(3*p+0)&3] = O0 + dw0 * dep;
        M[(3*p+1)>>2][(3*p+1)&3] = O1 + dw1 * dep;
        M[(3*p+2)>>2][(3*p+2)&3] = O2 + dw2 * dep;

        // scales
        const float sm = dep * mult;
        S[(3*p+0)>>2][(3*p+0)&3] = (SCALE_MIN_c + (SCALE_MAX_c - SCALE_MIN_c) / (1.0f + __expf(-ra.z))) * sm;
        S[(3*p+1)>>2][(3*p+1)&3] = (SCALE_MIN_c + (SCALE_MAX_c - SCALE_MIN_c) / (1.0f + __expf(-ra.w))) * sm;
        S[(3*p+2)>>2][(3*p+2)&3] = (SCALE_MIN_c + (SCALE_MAX_c - SCALE_MIN_c) / (1.0f + __expf(-rb.x))) * sm;

        // rotations: normalize raw[5:9] (xyzw) -> wxyz, then c2w_q * cam_q
        const float rx = rb.y, ry = rb.z, rz = rb.w, rwv = rc.x;
        const float rn = 1.0f / (sqrtf(rx*rx + ry*ry + rz*rz + rwv*rwv) + EPS_c);
        const float bw = rwv*rn, bx = rx*rn, by = ry*rn, bz = rz*rn;
        f4 wq;
        wq.x = aw*bw - ax*bx - ay*by - az*bz;
        wq.y = aw*bx + ax*bw + ay*bz - az*by;
        wq.z = aw*by - ax*bz + ay*bw + az*bx;
        wq.w = aw*bz + ax*by - ay*bx + az*bw;
        Rt[p] = wq;

        // harmonics
        Hm[(3*p+0)>>2][(3*p+0)&3] = rc.y;
        Hm[(3*p+1)>>2][(3*p+1)&3] = rc.z;
        Hm[(3*p+2)>>2][(3*p+2)&3] = rc.w;
    }

    // ---- dense per-thread output runs (nontemporal: no reuse, spare L2) ----
    f4* mo = reinterpret_cast<f4*>(out + MEANS_OFF  + g0 * 3);
    f4* so = reinterpret_cast<f4*>(out + SCALES_OFF + g0 * 3);
    f4* ro = reinterpret_cast<f4*>(out + ROT_OFF    + g0 * 4);
    f4* ho = reinterpret_cast<f4*>(out + HARM_OFF   + g0 * 3);
    f4* oo = reinterpret_cast<f4*>(out + OPAC_OFF   + g0);

    __builtin_nontemporal_store(M[0], mo + 0);
    __builtin_nontemporal_store(M[1], mo + 1);
    __builtin_nontemporal_store(M[2], mo + 2);
    __builtin_nontemporal_store(S[0], so + 0);
    __builtin_nontemporal_store(S[1], so + 1);
    __builtin_nontemporal_store(S[2], so + 2);
    __builtin_nontemporal_store(Rt[0], ro + 0);
    __builtin_nontemporal_store(Rt[1], ro + 1);
    __builtin_nontemporal_store(Rt[2], ro + 2);
    __builtin_nontemporal_store(Rt[3], ro + 3);
    __builtin_nontemporal_store(Hm[0], ho + 0);
    __builtin_nontemporal_store(Hm[1], ho + 1);
    __builtin_nontemporal_store(Hm[2], ho + 2);
    __builtin_nontemporal_store(op4, oo);
}

extern "C" void kernel_launch(void* const* d_in, const int* in_sizes, int n_in,
                              void* d_out, int out_size, void* d_ws, size_t ws_size,
                              hipStream_t stream) {
    const float* ext    = (const float*)d_in[0];
    const float* intr   = (const float*)d_in[1];
    const float* depths = (const float*)d_in[2];
    const float* opac   = (const float*)d_in[3];
    const float* raw    = (const float*)d_in[4];
    float* out = (float*)d_out;

    ga_kernel<<<TOTc / 1024, 256, 0, stream>>>(ext, intr, depths, opac, raw, out);
}

// Round 5
// 176.987 us; speedup vs baseline: 1.1985x; 1.1985x over previous
//
#include <hip/hip_runtime.h>
#include <math.h>

typedef float f4 __attribute__((ext_vector_type(4)));

#define Bc 4
#define Vc 4
#define Hc 256
#define Wc 384
#define HWc (Hc*Wc)               // 98304
#define TOTc (Bc*Vc*HWc)          // 1572864
#define SCALE_MIN_c 1e-05f
#define SCALE_MAX_c 30.0f
#define EPS_c 1e-08f

// Output section offsets (in floats)
#define MEANS_OFF  ((size_t)0)
#define SCALES_OFF ((size_t)TOTc*3)
#define ROT_OFF    ((size_t)TOTc*6)
#define HARM_OFF   ((size_t)TOTc*10)
#define OPAC_OFF   ((size_t)TOTc*13)

// 4 pixels per thread; 256 threads/block -> 1024 pixels/block.
// HWc/1024 = 96 blocks per view; 16 views -> 1536 blocks. View is block-uniform.
#define BLOCKS_PER_VIEW (HWc/1024)   // 96

__global__ __launch_bounds__(256) void ga_kernel(
    const float* __restrict__ ext,    // (B,V,4,4)
    const float* __restrict__ intr,   // (B,V,3,3)
    const float* __restrict__ depths, // (B,V,H,W)
    const float* __restrict__ opac,   // (B,V,H,W)
    const float* __restrict__ raw,    // (B,V,H,W,12)
    float* __restrict__ out)
{
    const int tid  = threadIdx.x;
    const int bid  = blockIdx.x;
    const int view = bid / BLOCKS_PER_VIEW;                  // block-uniform
    const int pix0 = (bid - view * BLOCKS_PER_VIEW) * 1024 + tid * 4;
    const size_t g0 = (size_t)view * HWc + (size_t)pix0;

    // ---- issue ALL per-thread input loads first (max MLP, 14 in flight) ----
    const f4* rp = reinterpret_cast<const f4*>(raw + g0 * 12);
    f4 rw[12];
    #pragma unroll
    for (int i = 0; i < 12; i++) rw[i] = rp[i];
    const f4 dep4 = *reinterpret_cast<const f4*>(depths + g0);
    const f4 op4  = *reinterpret_cast<const f4*>(opac + g0);

    // ---- per-view constants, computed redundantly by every lane (uniform) ----
    const float* E = ext + view * 16;
    // Rc2w = Rw2c^T
    const float R0 = E[0], R1 = E[4], R2 = E[8];
    const float R3 = E[1], R4 = E[5], R5 = E[9];
    const float R6 = E[2], R7 = E[6], R8 = E[10];
    const float t0 = E[3], t1 = E[7], t2 = E[11];
    const float O0 = -(R0*t0 + R1*t1 + R2*t2);
    const float O1 = -(R3*t0 + R4*t1 + R5*t2);
    const float O2 = -(R6*t0 + R7*t1 + R8*t2);

    const float* I = intr + view * 9;
    const float a00 = I[0]*(1.0f/Wc), a01 = I[1]*(1.0f/Wc), a02 = I[2]*(1.0f/Wc);
    const float a10 = I[3]*(1.0f/Hc), a11 = I[4]*(1.0f/Hc), a12 = I[5]*(1.0f/Hc);
    const float a20 = I[6],           a21 = I[7],           a22 = I[8];
    const float det = a00*(a11*a22 - a12*a21)
                    - a01*(a10*a22 - a12*a20)
                    + a02*(a10*a21 - a11*a20);
    const float id = 1.0f / det;
    const float K0 = (a11*a22 - a12*a21)*id;
    const float K1 = (a02*a21 - a01*a22)*id;
    const float K2 = (a01*a12 - a02*a11)*id;
    const float K3 = (a12*a20 - a10*a22)*id;
    const float K4 = (a00*a22 - a02*a20)*id;
    const float K5 = (a02*a10 - a00*a12)*id;
    const float K6 = (a10*a21 - a11*a20)*id;
    const float K7 = (a01*a20 - a00*a21)*id;
    const float K8 = (a00*a11 - a01*a10)*id;

    const float det2 = a00*a11 - a01*a10;
    const float psx = 1.0f/Wc, psy = 1.0f/Hc;
    const float mult = 0.1f * ((a11*psx - a01*psy) + (-a10*psx + a00*psy)) / det2;

    // c2w quaternion from Rc2w (matches _mat_to_quat_wxyz); branches are wave-uniform
    const float m00 = R0, m01 = R1, m02 = R2;
    const float m10 = R3, m11 = R4, m12 = R5;
    const float m20 = R6, m21 = R7, m22 = R8;
    const float qa0 = sqrtf(fmaxf(0.0f, 1.0f + m00 + m11 + m22));
    const float qa1 = sqrtf(fmaxf(0.0f, 1.0f + m00 - m11 - m22));
    const float qa2 = sqrtf(fmaxf(0.0f, 1.0f - m00 + m11 - m22));
    const float qa3 = sqrtf(fmaxf(0.0f, 1.0f - m00 - m11 + m22));
    int idx = 0; float best = qa0, qsel = qa0;
    if (qa1 > best) { idx = 1; best = qa1; }
    if (qa2 > best) { idx = 2; best = qa2; }
    if (qa3 > best) { idx = 3; best = qa3; }
    float c0, c1, c2, c3;
    if (idx == 0)      { c0 = qa0*qa0;   c1 = m21 - m12; c2 = m02 - m20; c3 = m10 - m01; qsel = qa0; }
    else if (idx == 1) { c0 = m21 - m12; c1 = qa1*qa1;   c2 = m10 + m01; c3 = m02 + m20; qsel = qa1; }
    else if (idx == 2) { c0 = m02 - m20; c1 = m10 + m01; c2 = qa2*qa2;   c3 = m12 + m21; qsel = qa2; }
    else               { c0 = m10 - m01; c1 = m20 + m02; c2 = m21 + m12; c3 = qa3*qa3;   qsel = qa3; }
    const float dd = 1.0f / (2.0f * fmaxf(qsel, 0.1f));
    float q0 = c0*dd, q1 = c1*dd, q2 = c2*dd, q3 = c3*dd;
    const float qn = 1.0f / sqrtf(q0*q0 + q1*q1 + q2*q2 + q3*q3);
    const float aw = q0*qn, ax = q1*qn, ay = q2*qn, az = q3*qn;

    // ---- per-pixel work (4 pixels, same image row) ----
    const int h  = pix0 / Wc;
    const int w0 = pix0 - h * Wc;
    const float ybase = (h + 0.5f) * (1.0f/Hc);
    const float dv[4] = { dep4.x, dep4.y, dep4.z, dep4.w };

    f4 M[3], S[3], Hm[3], Rt[4];

    #pragma unroll
    for (int p = 0; p < 4; p++) {
        const f4 ra = rw[3*p + 0];   // raw[0..3]
        const f4 rb = rw[3*p + 1];   // raw[4..7]
        const f4 rc = rw[3*p + 2];   // raw[8..11]
        const float dep = dv[p];

        const float x = (w0 + p + 0.5f) * (1.0f/Wc) + ra.x * (1.0f/Wc);
        const float y = ybase + ra.y * (1.0f/Hc);

        // d_cam = normalize(Kinv @ (x,y,1))
        float dc0 = K0*x + K1*y + K2;
        float dc1 = K3*x + K4*y + K5;
        float dc2 = K6*x + K7*y + K8;
        const float inl = rsqrtf(dc0*dc0 + dc1*dc1 + dc2*dc2);
        dc0 *= inl; dc1 *= inl; dc2 *= inl;

        // d_world = Rc2w @ d_cam
        const float dw0 = R0*dc0 + R1*dc1 + R2*dc2;
        const float dw1 = R3*dc0 + R4*dc1 + R5*dc2;
        const float dw2 = R6*dc0 + R7*dc1 + R8*dc2;

        // means
        M[(3*p+0)>>2][(3*p+0)&3] = O0 + dw0 * dep;
        M[(3*p+1)>>2][(3*p+1)&3] = O1 + dw1 * dep;
        M[(3*p+2)>>2][(3*p+2)&3] = O2 + dw2 * dep;

        // scales
        const float sm = dep * mult;
        S[(3*p+0)>>2][(3*p+0)&3] = (SCALE_MIN_c + (SCALE_MAX_c - SCALE_MIN_c) / (1.0f + __expf(-ra.z))) * sm;
        S[(3*p+1)>>2][(3*p+1)&3] = (SCALE_MIN_c + (SCALE_MAX_c - SCALE_MIN_c) / (1.0f + __expf(-ra.w))) * sm;
        S[(3*p+2)>>2][(3*p+2)&3] = (SCALE_MIN_c + (SCALE_MAX_c - SCALE_MIN_c) / (1.0f + __expf(-rb.x))) * sm;

        // rotations: normalize raw[5:9] (xyzw) -> wxyz, then c2w_q * cam_q
        const float rx = rb.y, ry = rb.z, rz = rb.w, rwv = rc.x;
        const float rn = 1.0f / (sqrtf(rx*rx + ry*ry + rz*rz + rwv*rwv) + EPS_c);
        const float bw = rwv*rn, bx = rx*rn, by = ry*rn, bz = rz*rn;
        f4 wq;
        wq.x = aw*bw - ax*bx - ay*by - az*bz;
        wq.y = aw*bx + ax*bw + ay*bz - az*by;
        wq.z = aw*by - ax*bz + ay*bw + az*bx;
        wq.w = aw*bz + ax*by - ay*bx + az*bw;
        Rt[p] = wq;

        // harmonics
        Hm[(3*p+0)>>2][(3*p+0)&3] = rc.y;
        Hm[(3*p+1)>>2][(3*p+1)&3] = rc.z;
        Hm[(3*p+2)>>2][(3*p+2)&3] = rc.w;
    }

    // ---- dense per-thread output runs, PLAIN stores (L2 write-combining) ----
    f4* mo = reinterpret_cast<f4*>(out + MEANS_OFF  + g0 * 3);
    f4* so = reinterpret_cast<f4*>(out + SCALES_OFF + g0 * 3);
    f4* ro = reinterpret_cast<f4*>(out + ROT_OFF    + g0 * 4);
    f4* ho = reinterpret_cast<f4*>(out + HARM_OFF   + g0 * 3);
    f4* oo = reinterpret_cast<f4*>(out + OPAC_OFF   + g0);

    mo[0] = M[0];  mo[1] = M[1];  mo[2] = M[2];
    so[0] = S[0];  so[1] = S[1];  so[2] = S[2];
    ro[0] = Rt[0]; ro[1] = Rt[1]; ro[2] = Rt[2]; ro[3] = Rt[3];
    ho[0] = Hm[0]; ho[1] = Hm[1]; ho[2] = Hm[2];
    *oo = op4;
}

extern "C" void kernel_launch(void* const* d_in, const int* in_sizes, int n_in,
                              void* d_out, int out_size, void* d_ws, size_t ws_size,
                              hipStream_t stream) {
    const float* ext    = (const float*)d_in[0];
    const float* intr   = (const float*)d_in[1];
    const float* depths = (const float*)d_in[2];
    const float* opac   = (const float*)d_in[3];
    const float* raw    = (const float*)d_in[4];
    float* out = (float*)d_out;

    ga_kernel<<<TOTc / 1024, 256, 0, stream>>>(ext, intr, depths, opac, raw, out);
}